// Round 2
// baseline (44926.715 us; speedup 1.0000x reference)
//
#include <hip/hip_runtime.h>
#include <hip/hip_cooperative_groups.h>
#include <cmath>

namespace cg = cooperative_groups;

#define BB 128
#define TT 365
#define DD 32
#define HH 512
// K = DD + HH = 544 reduction length per gate column.

// ---------------------------------------------------------------------------
// Persistent cooperative kernel: 512 WGs = 4 batch-blocks (32 b) x 128
// n-blocks (4 h-cols -> 16 gate-cols). W slice resident in LDS all steps.
// h exchanged through d_ws with AGENT-scope atomics (cross-XCD safe).
// ---------------------------------------------------------------------------
__global__ __launch_bounds__(256, 2)
void lstm_persistent(const float* __restrict__ x,
                     const float* __restrict__ Wx,
                     const float* __restrict__ Wh,
                     const float* __restrict__ bias,
                     float* __restrict__ out,
                     float* __restrict__ hws) {
  __shared__ float Wl[16][544];   // weight slice, c-major
  __shared__ float Ash[32][132];  // activation chunk [b][k], padded
  __shared__ float Zx[4][32][4];  // gate exchange
  __shared__ float Cs[32][4];     // persistent cell state
  __shared__ float BiasS[16];

  const int tid = threadIdx.x;
  const int ctile = tid >> 6;     // wave id: which gate
  const int ks = (tid >> 3) & 7;  // K-split (lane bits 3..5)
  const int btile = tid & 7;      // 4 batches each
  const int wg = blockIdx.x;
  const int bb = wg & 3;
  const int nb = wg >> 2;
  const int b0g = bb * 32;
  const int n0 = nb * 4;

  for (int idx = tid; idx < 16 * 544; idx += 256) {
    int zc = idx & 15;
    int k = idx >> 4;
    int gate = zc >> 2, nn = zc & 3;
    int col = gate * HH + n0 + nn;
    Wl[zc][k] = (k < DD) ? Wx[k * (4 * HH) + col] : Wh[(k - DD) * (4 * HH) + col];
  }
  if (tid < 16) {
    int gate = tid >> 2, nn = tid & 3;
    BiasS[tid] = bias[gate * HH + n0 + nn];
  }
  if (tid < 128) Cs[tid >> 2][tid & 3] = 0.f;

  float* buf0 = hws;
  float* buf1 = hws + BB * HH;
  int g0 = wg * 256 + tid;
  if (g0 < BB * HH)
    __hip_atomic_store(&buf0[g0], 0.f, __ATOMIC_RELAXED, __HIP_MEMORY_SCOPE_AGENT);

  cg::grid_group grid = cg::this_grid();
  __threadfence();
  grid.sync();

  for (int t = 0; t < TT; ++t) {
    const float* hprev = (t & 1) ? buf1 : buf0;
    float* hnext = (t & 1) ? buf0 : buf1;

    float acc[4][4];
#pragma unroll
    for (int i = 0; i < 4; ++i)
#pragma unroll
      for (int c = 0; c < 4; ++c) acc[i][c] = 0.f;

#pragma unroll
    for (int ch = 0; ch < 5; ++ch) {
      if (ch == 0) {
        int b_l = tid >> 3, kq = tid & 7;
        float4 v = ((const float4*)(x + ((size_t)(b0g + b_l) * TT + t) * DD))[kq];
        *(float4*)&Ash[b_l][kq * 4] = v;
      } else {
#pragma unroll
        for (int r = 0; r < 16; ++r) {
          int idx = tid + r * 256;      // 0..4095 -> 32 b x 128 k
          int b_l = idx >> 7, kk = idx & 127;
          Ash[b_l][kk] = __hip_atomic_load(
              hprev + (size_t)(b0g + b_l) * HH + (ch - 1) * 128 + kk,
              __ATOMIC_RELAXED, __HIP_MEMORY_SCOPE_AGENT);
        }
      }
      __syncthreads();

      const int kslice = (ch == 0) ? 4 : 16;
      const int koff = (ch == 0) ? 0 : DD + (ch - 1) * 128;
      const int kb = ks * kslice;

      for (int j = 0; j < kslice; j += 4) {
        float4 a4[4], w4[4];
#pragma unroll
        for (int i = 0; i < 4; ++i)
          a4[i] = *(const float4*)&Ash[btile * 4 + i][kb + j];
#pragma unroll
        for (int c = 0; c < 4; ++c)
          w4[c] = *(const float4*)&Wl[ctile * 4 + c][koff + kb + j];
#pragma unroll
        for (int i = 0; i < 4; ++i)
#pragma unroll
          for (int c = 0; c < 4; ++c)
            acc[i][c] += a4[i].x * w4[c].x + a4[i].y * w4[c].y +
                         a4[i].z * w4[c].z + a4[i].w * w4[c].w;
      }
      __syncthreads();
    }

#pragma unroll
    for (int i = 0; i < 4; ++i)
#pragma unroll
      for (int c = 0; c < 4; ++c) {
        float v = acc[i][c];
        v += __shfl_xor(v, 8);
        v += __shfl_xor(v, 16);
        v += __shfl_xor(v, 32);
        acc[i][c] = v;
      }

    if (ks == 0) {
#pragma unroll
      for (int i = 0; i < 4; ++i)
#pragma unroll
        for (int c = 0; c < 4; ++c)
          Zx[ctile][btile * 4 + i][c] = acc[i][c] + BiasS[ctile * 4 + c];
    }
    __syncthreads();

    if (tid < 128) {
      int b_l = tid >> 2, nn = tid & 3;
      float zi = Zx[0][b_l][nn], zf = Zx[1][b_l][nn];
      float zg = Zx[2][b_l][nn], zo = Zx[3][b_l][nn];
      float ig = 1.f / (1.f + __expf(-zi));
      float fg = 1.f / (1.f + __expf(-zf));
      float gv = tanhf(zg);
      float og = 1.f / (1.f + __expf(-zo));
      float cnew = fg * Cs[b_l][nn] + ig * gv;
      Cs[b_l][nn] = cnew;
      float hv = og * tanhf(cnew);
      int bg = b0g + b_l, col = n0 + nn;
      __hip_atomic_store(&hnext[(size_t)bg * HH + col], hv,
                         __ATOMIC_RELAXED, __HIP_MEMORY_SCOPE_AGENT);
      out[((size_t)bg * TT + t) * HH + col] = hv;
    }

    __threadfence();
    grid.sync();
  }
}

// ---------------------------------------------------------------------------
// Fallback path: one ordinary launch per timestep (kernel-boundary coherence).
// Same tiling; Wl re-staged each launch; c-state in global workspace.
// ---------------------------------------------------------------------------
__global__ void lstm_init(float* buf0, float* cst) {
  int i = blockIdx.x * blockDim.x + threadIdx.x;
  if (i < BB * HH) {
    buf0[i] = 0.f;
    cst[i] = 0.f;
  }
}

__global__ __launch_bounds__(256, 2)
void lstm_step(const float* __restrict__ x, const float* __restrict__ Wx,
               const float* __restrict__ Wh, const float* __restrict__ bias,
               float* __restrict__ out, const float* __restrict__ hprev,
               float* __restrict__ hnext, float* __restrict__ cst, int t) {
  __shared__ float Wl[16][544];
  __shared__ float Ash[32][132];
  __shared__ float Zx[4][32][4];
  __shared__ float BiasS[16];

  const int tid = threadIdx.x;
  const int ctile = tid >> 6;
  const int ks = (tid >> 3) & 7;
  const int btile = tid & 7;
  const int wg = blockIdx.x;
  const int bb = wg & 3;
  const int nb = wg >> 2;
  const int b0g = bb * 32;
  const int n0 = nb * 4;

  for (int idx = tid; idx < 16 * 544; idx += 256) {
    int zc = idx & 15;
    int k = idx >> 4;
    int gate = zc >> 2, nn = zc & 3;
    int col = gate * HH + n0 + nn;
    Wl[zc][k] = (k < DD) ? Wx[k * (4 * HH) + col] : Wh[(k - DD) * (4 * HH) + col];
  }
  if (tid < 16) {
    int gate = tid >> 2, nn = tid & 3;
    BiasS[tid] = bias[gate * HH + n0 + nn];
  }

  float acc[4][4];
#pragma unroll
  for (int i = 0; i < 4; ++i)
#pragma unroll
    for (int c = 0; c < 4; ++c) acc[i][c] = 0.f;

  __syncthreads();  // Wl ready

#pragma unroll
  for (int ch = 0; ch < 5; ++ch) {
    if (ch == 0) {
      int b_l = tid >> 3, kq = tid & 7;
      float4 v = ((const float4*)(x + ((size_t)(b0g + b_l) * TT + t) * DD))[kq];
      *(float4*)&Ash[b_l][kq * 4] = v;
    } else {
#pragma unroll
      for (int r = 0; r < 4; ++r) {
        int idx = tid + r * 256;
        int b_l = idx >> 5, kq = idx & 31;
        float4 v = ((const float4*)(hprev + (size_t)(b0g + b_l) * HH +
                                    (ch - 1) * 128))[kq];
        *(float4*)&Ash[b_l][kq * 4] = v;
      }
    }
    __syncthreads();

    const int kslice = (ch == 0) ? 4 : 16;
    const int koff = (ch == 0) ? 0 : DD + (ch - 1) * 128;
    const int kb = ks * kslice;

    for (int j = 0; j < kslice; j += 4) {
      float4 a4[4], w4[4];
#pragma unroll
      for (int i = 0; i < 4; ++i)
        a4[i] = *(const float4*)&Ash[btile * 4 + i][kb + j];
#pragma unroll
      for (int c = 0; c < 4; ++c)
        w4[c] = *(const float4*)&Wl[ctile * 4 + c][koff + kb + j];
#pragma unroll
      for (int i = 0; i < 4; ++i)
#pragma unroll
        for (int c = 0; c < 4; ++c)
          acc[i][c] += a4[i].x * w4[c].x + a4[i].y * w4[c].y +
                       a4[i].z * w4[c].z + a4[i].w * w4[c].w;
    }
    __syncthreads();
  }

#pragma unroll
  for (int i = 0; i < 4; ++i)
#pragma unroll
    for (int c = 0; c < 4; ++c) {
      float v = acc[i][c];
      v += __shfl_xor(v, 8);
      v += __shfl_xor(v, 16);
      v += __shfl_xor(v, 32);
      acc[i][c] = v;
    }

  if (ks == 0) {
#pragma unroll
    for (int i = 0; i < 4; ++i)
#pragma unroll
      for (int c = 0; c < 4; ++c)
        Zx[ctile][btile * 4 + i][c] = acc[i][c] + BiasS[ctile * 4 + c];
  }
  __syncthreads();

  if (tid < 128) {
    int b_l = tid >> 2, nn = tid & 3;
    float zi = Zx[0][b_l][nn], zf = Zx[1][b_l][nn];
    float zg = Zx[2][b_l][nn], zo = Zx[3][b_l][nn];
    float ig = 1.f / (1.f + __expf(-zi));
    float fg = 1.f / (1.f + __expf(-zf));
    float gv = tanhf(zg);
    float og = 1.f / (1.f + __expf(-zo));
    int bg = b0g + b_l, col = n0 + nn;
    size_t cidx = (size_t)bg * HH + col;
    float cnew = fg * cst[cidx] + ig * gv;
    cst[cidx] = cnew;
    float hv = og * tanhf(cnew);
    hnext[cidx] = hv;
    out[((size_t)bg * TT + t) * HH + col] = hv;
  }
}

extern "C" void kernel_launch(void* const* d_in, const int* in_sizes, int n_in,
                              void* d_out, int out_size, void* d_ws, size_t ws_size,
                              hipStream_t stream) {
  const float* x = (const float*)d_in[0];
  const float* Wx = (const float*)d_in[1];
  const float* Wh = (const float*)d_in[2];
  const float* bv = (const float*)d_in[3];
  float* out = (float*)d_out;
  float* hws = (float*)d_ws;  // buf0 | buf1 | cst : 3 * 256 KB

  void* args[] = {(void*)&x, (void*)&Wx, (void*)&Wh,
                  (void*)&bv, (void*)&out, (void*)&hws};
  hipError_t err = hipLaunchCooperativeKernel(
      reinterpret_cast<void*>(lstm_persistent), dim3(512), dim3(256), args, 0,
      stream);
  if (err != hipSuccess) {
    (void)hipGetLastError();  // clear sticky error, use fallback path
    float* buf0 = hws;
    float* buf1 = hws + BB * HH;
    float* cst = hws + 2 * BB * HH;
    lstm_init<<<dim3(256), dim3(256), 0, stream>>>(buf0, cst);
    for (int t = 0; t < TT; ++t) {
      const float* hp = (t & 1) ? buf1 : buf0;
      float* hn = (t & 1) ? buf0 : buf1;
      lstm_step<<<dim3(512), dim3(256), 0, stream>>>(x, Wx, Wh, bv, out, hp, hn,
                                                     cst, t);
    }
  }
}

// Round 3
// 13187.132 us; speedup vs baseline: 3.4069x; 3.4069x over previous
//
#include <hip/hip_runtime.h>
#include <cmath>

#define BB 128
#define TT 365
#define DD 32
#define HH 512
#define G4H 2048  // 4*HH

// ws layout (floats): buf0 [0,65536) | buf1 [65536,131072) | bar [131072,+256 uints)
//                     | cst [131328, +65536) (fallback only)
// hipMemsetAsync zeroes [0, 787456) bytes each call.

__device__ __forceinline__ float sigf(float z) { return 1.f / (1.f + __expf(-z)); }

// ---------------------------------------------------------------------------
// Persistent kernel: 512 WGs = 4 batch-blocks (32 b) x 128 n-blocks (4 h-cols
// -> 16 gate-cols). W slice lives in LDS all 365 steps. Lane map: ks=tid&7
// (K-split, conflict-free contiguous LDS reads), btile=(tid>>3)&7, ctile=wave.
// Per-batch-block barrier (128 WGs) on a monotonic counter; h exchanged via
// agent-scope atomics (coherent at L3, no L2 flush needed).
// ---------------------------------------------------------------------------
__global__ __launch_bounds__(256, 2)
void lstm_persistent(const float* __restrict__ x,
                     const float* __restrict__ Wx,
                     const float* __restrict__ Wh,
                     const float* __restrict__ bias,
                     float* __restrict__ out,
                     float* __restrict__ hws) {
  __shared__ float Wl[16 * 544];      // 34816 B, row stride 544 (2176B % 128 == 0)
  __shared__ float Ash[2][32 * 128];  // 32768 B, double-buffered h chunk
  __shared__ float Xs[32 * 32];       // 4096 B
  __shared__ float Zx[4][32][4];      // 2048 B
  __shared__ float Cs[32][4];         // 512 B
  __shared__ float BiasS[16];
  // total 74304 B -> 2 WGs/CU

  const int tid = threadIdx.x;
  const int ks = tid & 7;          // K-split: lane bits 0..2 (contiguous reads)
  const int btile = (tid >> 3) & 7;
  const int ctile = tid >> 6;      // wave = gate
  const int wg = blockIdx.x;
  const int bb = wg & 3;
  const int nb = wg >> 2;
  const int b0g = bb * 32;
  const int n0 = nb * 4;

  for (int idx = tid; idx < 16 * 544; idx += 256) {
    int zc = idx & 15, k = idx >> 4;
    int col = (zc >> 2) * HH + n0 + (zc & 3);
    Wl[zc * 544 + k] = (k < DD) ? Wx[k * G4H + col] : Wh[(k - DD) * G4H + col];
  }
  if (tid < 16) BiasS[tid] = bias[(tid >> 2) * HH + n0 + (tid & 3)];
  if (tid < 128) Cs[tid >> 2][tid & 3] = 0.f;

  float* buf0 = hws;
  float* buf1 = hws + BB * HH;
  unsigned int* bar = (unsigned int*)(hws + 2 * BB * HH) + bb * 64;

  __syncthreads();  // Wl ready (h0 = 0 comes from host-side memset)

  for (int t = 0; t < TT; ++t) {
    const float* hprev = (t & 1) ? buf1 : buf0;
    float* hnext = (t & 1) ? buf0 : buf1;

    // ---- stage x slice (normal loads; input buffer is coherent)
    {
      int b_l = tid >> 3, kq = tid & 7;
      float4 v =
          *(const float4*)(x + ((size_t)(b0g + b_l) * TT + t) * DD + kq * 4);
      *(float4*)&Xs[b_l * 32 + kq * 4] = v;
    }
    // ---- prefetch h chunk 0 (agent-scope 64-bit atomic loads)
    unsigned long long pre[8];
#pragma unroll
    for (int r = 0; r < 8; ++r) {
      int fidx = r * 256 + tid;
      int b_l = fidx >> 6, kk = fidx & 63;
      pre[r] = __hip_atomic_load(
          (const unsigned long long*)(hprev + (size_t)(b0g + b_l) * HH + kk * 2),
          __ATOMIC_RELAXED, __HIP_MEMORY_SCOPE_AGENT);
    }
#pragma unroll
    for (int r = 0; r < 8; ++r) {
      int fidx = r * 256 + tid;
      int b_l = fidx >> 6, kk = fidx & 63;
      *(unsigned long long*)&Ash[0][b_l * 128 + kk * 2] = pre[r];
    }
    __syncthreads();

    float acc[4][4];
#pragma unroll
    for (int i = 0; i < 4; ++i)
#pragma unroll
      for (int c = 0; c < 4; ++c) acc[i][c] = 0.f;

    auto mac4 = [&](const float* Abase, int rstride, const float* Wbase) {
      float4 a4[4], w4[4];
#pragma unroll
      for (int i = 0; i < 4; ++i)
        a4[i] = *(const float4*)(Abase + (btile * 4 + i) * rstride);
#pragma unroll
      for (int c = 0; c < 4; ++c) w4[c] = *(const float4*)(Wbase + c * 544);
#pragma unroll
      for (int i = 0; i < 4; ++i)
#pragma unroll
        for (int c = 0; c < 4; ++c)
          acc[i][c] += a4[i].x * w4[c].x + a4[i].y * w4[c].y +
                       a4[i].z * w4[c].z + a4[i].w * w4[c].w;
    };

#pragma unroll
    for (int ch = 0; ch < 4; ++ch) {
      // issue next chunk's loads early; latency hides under this chunk's FMAs
      if (ch < 3) {
#pragma unroll
        for (int r = 0; r < 8; ++r) {
          int fidx = r * 256 + tid;
          int b_l = fidx >> 6, kk = fidx & 63;
          pre[r] = __hip_atomic_load(
              (const unsigned long long*)(hprev + (size_t)(b0g + b_l) * HH +
                                          (ch + 1) * 128 + kk * 2),
              __ATOMIC_RELAXED, __HIP_MEMORY_SCOPE_AGENT);
        }
      }
      if (ch == 0) mac4(&Xs[ks * 4], 32, &Wl[(ctile * 4) * 544 + ks * 4]);
#pragma unroll
      for (int j = 0; j < 4; ++j)
        mac4(&Ash[ch & 1][j * 32 + ks * 4], 128,
             &Wl[(ctile * 4) * 544 + DD + ch * 128 + j * 32 + ks * 4]);
      if (ch < 3) {
#pragma unroll
        for (int r = 0; r < 8; ++r) {
          int fidx = r * 256 + tid;
          int b_l = fidx >> 6, kk = fidx & 63;
          *(unsigned long long*)&Ash[(ch + 1) & 1][b_l * 128 + kk * 2] = pre[r];
        }
      }
      __syncthreads();
    }

    // reduce over ks (lane bits 0..2)
#pragma unroll
    for (int i = 0; i < 4; ++i)
#pragma unroll
      for (int c = 0; c < 4; ++c) {
        float v = acc[i][c];
        v += __shfl_xor(v, 1);
        v += __shfl_xor(v, 2);
        v += __shfl_xor(v, 4);
        acc[i][c] = v;
      }

    if (ks == 0) {
#pragma unroll
      for (int i = 0; i < 4; ++i)
#pragma unroll
        for (int c = 0; c < 4; ++c)
          Zx[ctile][btile * 4 + i][c] = acc[i][c] + BiasS[ctile * 4 + c];
    }
    __syncthreads();

    if (tid < 128) {
      int b_l = tid >> 2, nn = tid & 3;
      float zi = Zx[0][b_l][nn], zf = Zx[1][b_l][nn];
      float zg = Zx[2][b_l][nn], zo = Zx[3][b_l][nn];
      float cnew = sigf(zf) * Cs[b_l][nn] + sigf(zi) * tanhf(zg);
      Cs[b_l][nn] = cnew;
      float hv = sigf(zo) * tanhf(cnew);
      int bg = b0g + b_l, col = n0 + nn;
      __hip_atomic_store(&hnext[(size_t)bg * HH + col], hv, __ATOMIC_RELAXED,
                         __HIP_MEMORY_SCOPE_AGENT);
      out[((size_t)bg * TT + t) * HH + col] = hv;
    }
    __syncthreads();  // drains vmcnt(0): h stores at L3 before anyone arrives

    // per-batch-block barrier: monotonic counter, 128 WGs
    if (tid == 0) {
      __hip_atomic_fetch_add(bar, 1u, __ATOMIC_RELAXED,
                             __HIP_MEMORY_SCOPE_AGENT);
      unsigned int target = 128u * (unsigned)(t + 1);
      while (__hip_atomic_load(bar, __ATOMIC_RELAXED,
                               __HIP_MEMORY_SCOPE_AGENT) < target) {
      }
    }
    __syncthreads();
  }
}

// ---------------------------------------------------------------------------
// Fallback: one launch per timestep (kernel-boundary coherence). Only used if
// the cooperative launch is rejected.
// ---------------------------------------------------------------------------
__global__ __launch_bounds__(256, 2)
void lstm_step(const float* __restrict__ x, const float* __restrict__ Wx,
               const float* __restrict__ Wh, const float* __restrict__ bias,
               float* __restrict__ out, const float* __restrict__ hprev,
               float* __restrict__ hnext, float* __restrict__ cst, int t) {
  __shared__ float Wl[16 * 544];
  __shared__ float Ash[32 * 128];
  __shared__ float Xs[32 * 32];
  __shared__ float Zx[4][32][4];
  __shared__ float BiasS[16];

  const int tid = threadIdx.x;
  const int ks = tid & 7;
  const int btile = (tid >> 3) & 7;
  const int ctile = tid >> 6;
  const int wg = blockIdx.x;
  const int bb = wg & 3;
  const int nb = wg >> 2;
  const int b0g = bb * 32;
  const int n0 = nb * 4;

  for (int idx = tid; idx < 16 * 544; idx += 256) {
    int zc = idx & 15, k = idx >> 4;
    int col = (zc >> 2) * HH + n0 + (zc & 3);
    Wl[zc * 544 + k] = (k < DD) ? Wx[k * G4H + col] : Wh[(k - DD) * G4H + col];
  }
  if (tid < 16) BiasS[tid] = bias[(tid >> 2) * HH + n0 + (tid & 3)];

  {
    int b_l = tid >> 3, kq = tid & 7;
    float4 v = *(const float4*)(x + ((size_t)(b0g + b_l) * TT + t) * DD + kq * 4);
    *(float4*)&Xs[b_l * 32 + kq * 4] = v;
  }

  float acc[4][4];
#pragma unroll
  for (int i = 0; i < 4; ++i)
#pragma unroll
    for (int c = 0; c < 4; ++c) acc[i][c] = 0.f;

  auto mac4 = [&](const float* Abase, int rstride, const float* Wbase) {
    float4 a4[4], w4[4];
#pragma unroll
    for (int i = 0; i < 4; ++i)
      a4[i] = *(const float4*)(Abase + (btile * 4 + i) * rstride);
#pragma unroll
    for (int c = 0; c < 4; ++c) w4[c] = *(const float4*)(Wbase + c * 544);
#pragma unroll
    for (int i = 0; i < 4; ++i)
#pragma unroll
      for (int c = 0; c < 4; ++c)
        acc[i][c] += a4[i].x * w4[c].x + a4[i].y * w4[c].y +
                     a4[i].z * w4[c].z + a4[i].w * w4[c].w;
  };

  for (int ch = 0; ch < 4; ++ch) {
    __syncthreads();
    for (int r = 0; r < 4; ++r) {
      int fidx = r * 256 + tid;  // 1024 float4s? no: 32*128 floats = 1024 f4
      int b_l = fidx >> 5, kq = fidx & 31;
      float4 v = *(const float4*)(hprev + (size_t)(b0g + b_l) * HH + ch * 128 +
                                  kq * 4);
      *(float4*)&Ash[b_l * 128 + kq * 4] = v;
    }
    __syncthreads();
    if (ch == 0) mac4(&Xs[ks * 4], 32, &Wl[(ctile * 4) * 544 + ks * 4]);
#pragma unroll
    for (int j = 0; j < 4; ++j)
      mac4(&Ash[j * 32 + ks * 4], 128,
           &Wl[(ctile * 4) * 544 + DD + ch * 128 + j * 32 + ks * 4]);
  }

#pragma unroll
  for (int i = 0; i < 4; ++i)
#pragma unroll
    for (int c = 0; c < 4; ++c) {
      float v = acc[i][c];
      v += __shfl_xor(v, 1);
      v += __shfl_xor(v, 2);
      v += __shfl_xor(v, 4);
      acc[i][c] = v;
    }

  if (ks == 0) {
#pragma unroll
    for (int i = 0; i < 4; ++i)
#pragma unroll
      for (int c = 0; c < 4; ++c)
        Zx[ctile][btile * 4 + i][c] = acc[i][c] + BiasS[ctile * 4 + c];
  }
  __syncthreads();

  if (tid < 128) {
    int b_l = tid >> 2, nn = tid & 3;
    float zi = Zx[0][b_l][nn], zf = Zx[1][b_l][nn];
    float zg = Zx[2][b_l][nn], zo = Zx[3][b_l][nn];
    int bg = b0g + b_l, col = n0 + nn;
    size_t cidx = (size_t)bg * HH + col;
    float cnew = sigf(zf) * cst[cidx] + sigf(zi) * tanhf(zg);
    cst[cidx] = cnew;
    float hv = sigf(zo) * tanhf(cnew);
    hnext[cidx] = hv;
    out[((size_t)bg * TT + t) * HH + col] = hv;
  }
}

extern "C" void kernel_launch(void* const* d_in, const int* in_sizes, int n_in,
                              void* d_out, int out_size, void* d_ws, size_t ws_size,
                              hipStream_t stream) {
  const float* x = (const float*)d_in[0];
  const float* Wx = (const float*)d_in[1];
  const float* Wh = (const float*)d_in[2];
  const float* bv = (const float*)d_in[3];
  float* out = (float*)d_out;
  float* hws = (float*)d_ws;

  // zero: buf0 | buf1 | barrier counters | cst  = (3*65536 + 256) * 4 bytes
  hipMemsetAsync(d_ws, 0, (size_t)(3 * 65536 + 256) * 4, stream);

  void* args[] = {(void*)&x, (void*)&Wx, (void*)&Wh,
                  (void*)&bv, (void*)&out, (void*)&hws};
  hipError_t err = hipLaunchCooperativeKernel(
      reinterpret_cast<void*>(lstm_persistent), dim3(512), dim3(256), args, 0,
      stream);
  if (err != hipSuccess) {
    (void)hipGetLastError();
    float* buf0 = hws;
    float* buf1 = hws + BB * HH;
    float* cst = hws + 2 * BB * HH + 256;
    for (int t = 0; t < TT; ++t) {
      const float* hp = (t & 1) ? buf1 : buf0;
      float* hn = (t & 1) ? buf0 : buf1;
      lstm_step<<<dim3(512), dim3(256), 0, stream>>>(x, Wx, Wh, bv, out, hp, hn,
                                                     cst, t);
    }
  }
}